// Round 1
// 436.624 us; speedup vs baseline: 1.1170x; 1.1170x over previous
//
#include <hip/hip_runtime.h>

// ---------------------------------------------------------------------------
// localAE: two GCNConv layers (128->64 encode, 64->128 decode), N=100000,
// E=1.6M.  out[n] = dinv[n] * (hs[n] + sum_{e: dst==n} hs[src_e]) + b
// where hs = (X @ W) * dinv[row],  dinv = rsqrt(1 + indegree).
//
// Round 3: owner-partitioned bucket build. Old bucket_kernel was scattered-
// write bound: WRITE_SIZE 96 MB for a 6.4 MB payload (every 4B csr store ->
// 64B line writeback; a node's edges arrive from all 8 XCDs so per-XCD L2s
// can never merge same-line writes). Now group g = blockIdx&7 (round-robin
// XCD heuristic) commits only edges with owner(dst)==g, so each node's
// bucket line is written by exactly one XCD and merges in its L2 before
// writeback. Reads are 8x amplified but LLC-resident (edge list = 12.8 MB).
// Correctness is independent of the XCD mapping (atomics are device-scope);
// only the merging benefit depends on it.
// ---------------------------------------------------------------------------

#define OWNER_OF(d) (((d) >> 4) & 7)   // >>4 keeps a 64B cursor line single-owner

__global__ __launch_bounds__(256)
void bucket_kernel(const int* __restrict__ src, const int* __restrict__ dst,
                   int E, int* __restrict__ cursor, int* __restrict__ csr, int cap)
{
    const int g     = blockIdx.x & 7;          // XCD heuristic (round-robin dispatch)
    const int chunk = blockIdx.x >> 3;         // edge window, shared by all 8 groups
    const int base  = (chunk * 256 + threadIdx.x) * 4;

    if (base + 4 <= E) {
        const int4 d4 = *reinterpret_cast<const int4*>(dst + base);
        #pragma unroll
        for (int k = 0; k < 4; ++k) {
            const int d = (&d4.x)[k];
            if (OWNER_OF(d) == g) {
                const int pos = atomicAdd(&cursor[d], 1);
                if (pos < cap) csr[(size_t)d * cap + pos] = src[base + k];
            }
        }
    } else {
        for (int i = base; i < E; ++i) {
            const int d = dst[i];
            if (OWNER_OF(d) == g) {
                const int pos = atomicAdd(&cursor[d], 1);
                if (pos < cap) csr[(size_t)d * cap + pos] = src[i];
            }
        }
    }
}

__global__ __launch_bounds__(256)
void dinv_kernel(const int* __restrict__ cnt, float* __restrict__ dinv, int M) {
    int i = blockIdx.x * 256 + threadIdx.x;
    if (i < M) dinv[i] = rsqrtf((float)cnt[i] + 1.0f);   // +1 self-loop
}

// GEMM  hs[m, :] = (X[m, :] @ W) * dinv[m].
// Block: 256 threads, TM=64 rows.  LDS: W[K][N] + X tile [TM][K].
template<int K, int N>
__global__ __launch_bounds__(256)
void gemm_scale(const float* __restrict__ X, const float* __restrict__ W,
                const float* __restrict__ dinv, float* __restrict__ hs, int M)
{
    constexpr int TM  = 64;
    constexpr int QPR = K / 4;      // float4 quads per X row
    __shared__ float Ws[K * N];
    __shared__ float Xs[TM * K];

    const int tid  = threadIdx.x;
    const int row0 = blockIdx.x * TM;

    for (int i = tid; i < K * N / 4; i += 256) {
        float4 v = reinterpret_cast<const float4*>(W)[i];
        *reinterpret_cast<float4*>(&Ws[i * 4]) = v;
    }
    for (int i = tid; i < TM * QPR; i += 256) {
        int r = i / QPR, q = i - r * QPR;
        int gr = row0 + r;
        float4 v = make_float4(0.f, 0.f, 0.f, 0.f);
        if (gr < M) v = reinterpret_cast<const float4*>(X)[(size_t)gr * QPR + q];
        *reinterpret_cast<float4*>(&Xs[r * K + q * 4]) = v;
    }
    __syncthreads();

    constexpr int CG  = N / 4;          // column groups (4 cols each)
    constexpr int RPT = N / 16;         // rows per thread (4 or 8)
    const int c0 = (tid % CG) * 4;
    const int r0 = (tid / CG) * RPT;

    float a[RPT][4];
    #pragma unroll
    for (int rr = 0; rr < RPT; ++rr) {
        a[rr][0] = 0.f; a[rr][1] = 0.f; a[rr][2] = 0.f; a[rr][3] = 0.f;
    }

    #pragma unroll 4
    for (int k = 0; k < K; ++k) {
        const float4 wv = *reinterpret_cast<const float4*>(&Ws[k * N + c0]);
        #pragma unroll
        for (int rr = 0; rr < RPT; ++rr) {
            const float xv = Xs[(r0 + rr) * K + k];
            a[rr][0] += xv * wv.x;
            a[rr][1] += xv * wv.y;
            a[rr][2] += xv * wv.z;
            a[rr][3] += xv * wv.w;
        }
    }

    #pragma unroll
    for (int rr = 0; rr < RPT; ++rr) {
        const int gr = row0 + r0 + rr;
        if (gr < M) {
            const float d = dinv[gr];
            float4 v;
            v.x = a[rr][0] * d; v.y = a[rr][1] * d;
            v.z = a[rr][2] * d; v.w = a[rr][3] * d;
            *reinterpret_cast<float4*>(&hs[(size_t)gr * N + c0]) = v;
        }
    }
}

// Wave-per-node gather aggregation, finalize fused:
//   out[n] = dinv[n] * (hs[n] + sum_j hs[csr[n][j]]) + bias
// C=64: 1 float/lane; C=128: float2/lane. Edge-index loads are wave-uniform
// (n pinned to SGPR via readfirstlane) -> scalar loads; gathers are coalesced
// 256/512 B per wave. Unroll 8 for deeper MLP (gathers are LLC-latency bound).
template<int C>
__global__ __launch_bounds__(256)
void gcn_agg(const float* __restrict__ hs, const int* __restrict__ csr,
             const int* __restrict__ cnt, const float* __restrict__ dinv,
             const float* __restrict__ bias, float* __restrict__ out,
             int M, int cap)
{
    const int lane = threadIdx.x & 63;
    int n = (blockIdx.x * 256 + threadIdx.x) >> 6;
    if (n >= M) return;
    n = __builtin_amdgcn_readfirstlane(n);
    int deg = cnt[n];
    if (deg > cap) deg = cap;
    const int* __restrict__ lst = csr + (size_t)n * cap;
    const float dv = dinv[n];

    if constexpr (C == 64) {
        float acc = hs[(size_t)n * 64 + lane];
        int j = 0;
        for (; j + 8 <= deg; j += 8) {
            const int s0 = lst[j],     s1 = lst[j + 1], s2 = lst[j + 2], s3 = lst[j + 3];
            const int s4 = lst[j + 4], s5 = lst[j + 5], s6 = lst[j + 6], s7 = lst[j + 7];
            const float v0 = hs[(size_t)s0 * 64 + lane];
            const float v1 = hs[(size_t)s1 * 64 + lane];
            const float v2 = hs[(size_t)s2 * 64 + lane];
            const float v3 = hs[(size_t)s3 * 64 + lane];
            const float v4 = hs[(size_t)s4 * 64 + lane];
            const float v5 = hs[(size_t)s5 * 64 + lane];
            const float v6 = hs[(size_t)s6 * 64 + lane];
            const float v7 = hs[(size_t)s7 * 64 + lane];
            acc += ((v0 + v1) + (v2 + v3)) + ((v4 + v5) + (v6 + v7));
        }
        for (; j + 4 <= deg; j += 4) {
            const int s0 = lst[j], s1 = lst[j + 1], s2 = lst[j + 2], s3 = lst[j + 3];
            const float v0 = hs[(size_t)s0 * 64 + lane];
            const float v1 = hs[(size_t)s1 * 64 + lane];
            const float v2 = hs[(size_t)s2 * 64 + lane];
            const float v3 = hs[(size_t)s3 * 64 + lane];
            acc += (v0 + v1) + (v2 + v3);
        }
        for (; j < deg; ++j) acc += hs[(size_t)lst[j] * 64 + lane];
        out[(size_t)n * 64 + lane] = acc * dv + bias[lane];
    } else {
        const float2* __restrict__ h2 = reinterpret_cast<const float2*>(hs);
        float2 acc = h2[(size_t)n * 64 + lane];
        int j = 0;
        for (; j + 8 <= deg; j += 8) {
            const int s0 = lst[j],     s1 = lst[j + 1], s2 = lst[j + 2], s3 = lst[j + 3];
            const int s4 = lst[j + 4], s5 = lst[j + 5], s6 = lst[j + 6], s7 = lst[j + 7];
            const float2 v0 = h2[(size_t)s0 * 64 + lane];
            const float2 v1 = h2[(size_t)s1 * 64 + lane];
            const float2 v2 = h2[(size_t)s2 * 64 + lane];
            const float2 v3 = h2[(size_t)s3 * 64 + lane];
            const float2 v4 = h2[(size_t)s4 * 64 + lane];
            const float2 v5 = h2[(size_t)s5 * 64 + lane];
            const float2 v6 = h2[(size_t)s6 * 64 + lane];
            const float2 v7 = h2[(size_t)s7 * 64 + lane];
            acc.x += ((v0.x + v1.x) + (v2.x + v3.x)) + ((v4.x + v5.x) + (v6.x + v7.x));
            acc.y += ((v0.y + v1.y) + (v2.y + v3.y)) + ((v4.y + v5.y) + (v6.y + v7.y));
        }
        for (; j + 4 <= deg; j += 4) {
            const int s0 = lst[j], s1 = lst[j + 1], s2 = lst[j + 2], s3 = lst[j + 3];
            const float2 v0 = h2[(size_t)s0 * 64 + lane];
            const float2 v1 = h2[(size_t)s1 * 64 + lane];
            const float2 v2 = h2[(size_t)s2 * 64 + lane];
            const float2 v3 = h2[(size_t)s3 * 64 + lane];
            acc.x += (v0.x + v1.x) + (v2.x + v3.x);
            acc.y += (v0.y + v1.y) + (v2.y + v3.y);
        }
        for (; j < deg; ++j) {
            const float2 v = h2[(size_t)lst[j] * 64 + lane];
            acc.x += v.x; acc.y += v.y;
        }
        const float2 b2 = reinterpret_cast<const float2*>(bias)[lane];
        float2 o;
        o.x = acc.x * dv + b2.x;
        o.y = acc.y * dv + b2.y;
        reinterpret_cast<float2*>(out)[(size_t)n * 64 + lane] = o;
    }
}

extern "C" void kernel_launch(void* const* d_in, const int* in_sizes, int n_in,
                              void* d_out, int out_size, void* d_ws, size_t ws_size,
                              hipStream_t stream)
{
    const float* x    = (const float*)d_in[0];   // [M,128]
    const int*   ei   = (const int*)  d_in[1];   // [2,E]
    const float* Wenc = (const float*)d_in[2];   // [128,64]
    const float* benc = (const float*)d_in[3];   // [64]
    const float* Wdec = (const float*)d_in[4];   // [64,128]
    const float* bdec = (const float*)d_in[5];   // [128]

    const int M = in_sizes[0] / 128;             // 100000
    const int E = in_sizes[1] / 2;               // 1600000
    const int* src  = ei;
    const int* dstv = ei + E;

    float* emb   = (float*)d_out;                       // [M,64]
    float* recon = (float*)d_out + (size_t)M * 64;      // [M,128]

    // workspace layout
    float* hs     = (float*)d_ws;                        // M*128 f32 (51.2 MB)
    int*   cursor = (int*)d_ws + (size_t)M * 128;        // M ints (count per dst)
    float* dinv   = (float*)((int*)d_ws + (size_t)M * 129);
    int*   csr    = (int*)d_ws + (size_t)M * 130;        // M*cap ints

    const size_t used = (size_t)M * 130 * 4;
    int cap = 64;                                        // Poisson(16): P(deg>64) ~ 1e-50
    const size_t avail = (ws_size > used) ? (ws_size - used) / ((size_t)M * 4) : 0;
    if ((size_t)cap > avail) cap = (int)avail;

    hipMemsetAsync(cursor, 0, (size_t)M * sizeof(int), stream);

    // 8 owner groups x edge windows of 1024 (4 edges/thread, int4 dst loads)
    const int chunks = (E + 1023) / 1024;
    bucket_kernel<<<chunks * 8, 256, 0, stream>>>(src, dstv, E, cursor, csr, cap);
    dinv_kernel<<<(M + 255) / 256, 256, 0, stream>>>(cursor, dinv, M);

    const int aggBlocks = (M + 3) / 4;   // 4 waves (nodes) per 256-thread block

    // ---- layer 1: encode 128 -> 64 ----
    gemm_scale<128, 64><<<(M + 63) / 64, 256, 0, stream>>>(x, Wenc, dinv, hs, M);
    gcn_agg<64><<<aggBlocks, 256, 0, stream>>>(hs, csr, cursor, dinv, benc, emb, M, cap);

    // ---- layer 2: decode 64 -> 128 ----
    gemm_scale<64, 128><<<(M + 63) / 64, 256, 0, stream>>>(emb, Wdec, dinv, hs, M);
    gcn_agg<128><<<aggBlocks, 256, 0, stream>>>(hs, csr, cursor, dinv, bdec, recon, M, cap);
}

// Round 2
// 380.502 us; speedup vs baseline: 1.2817x; 1.1475x over previous
//
#include <hip/hip_runtime.h>

// ---------------------------------------------------------------------------
// localAE: two GCNConv layers (128->64 encode, 64->128 decode), N=100000,
// E=1.6M.  out[n] = dinv[n] * (hs[n] + sum_{e: dst==n} hs[src_e]) + b
// where hs = (X @ W) * dinv[row],  dinv = rsqrt(1 + indegree).
//
// Round 4: layer-2 aggregation moved into 64-dim embedding space.
// Old layer-2 agg gathered 512B rows from a 51.2MB array (FETCH 405MB,
// 121us). Aggregation commutes with the linear decode:
//   recon[n] = dinv[n] * ((emb[n]*dinv[n] + sum_src emb[src]*dinv[src]) @ Wdec) + b
// so we aggregate 256B rows from the 25.6MB emb array (dinv[src] is a free
// wave-uniform scalar load from the L2-resident 400KB dinv), then run the
// dense 64->128 GEMM with row-scale + bias epilogue.
// ---------------------------------------------------------------------------

#define OWNER_OF(d) (((d) >> 4) & 7)   // >>4 keeps a 64B cursor line single-owner

// Owner-partitioned bucket build (round 3): group g = blockIdx&7 commits only
// edges with owner(dst)==g so each node's csr lines are written by one XCD
// and merge in its L2 (WRITE_SIZE 96MB -> ~payload). Reads are 8x amplified
// but LLC-resident. Correctness independent of the XCD mapping.
__global__ __launch_bounds__(256)
void bucket_kernel(const int* __restrict__ src, const int* __restrict__ dst,
                   int E, int* __restrict__ cursor, int* __restrict__ csr, int cap)
{
    const int g     = blockIdx.x & 7;          // XCD heuristic (round-robin dispatch)
    const int chunk = blockIdx.x >> 3;         // edge window, shared by all 8 groups
    const int base  = (chunk * 256 + threadIdx.x) * 4;

    if (base + 4 <= E) {
        const int4 d4 = *reinterpret_cast<const int4*>(dst + base);
        #pragma unroll
        for (int k = 0; k < 4; ++k) {
            const int d = (&d4.x)[k];
            if (OWNER_OF(d) == g) {
                const int pos = atomicAdd(&cursor[d], 1);
                if (pos < cap) csr[(size_t)d * cap + pos] = src[base + k];
            }
        }
    } else {
        for (int i = base; i < E; ++i) {
            const int d = dst[i];
            if (OWNER_OF(d) == g) {
                const int pos = atomicAdd(&cursor[d], 1);
                if (pos < cap) csr[(size_t)d * cap + pos] = src[i];
            }
        }
    }
}

__global__ __launch_bounds__(256)
void dinv_kernel(const int* __restrict__ cnt, float* __restrict__ dinv, int M) {
    int i = blockIdx.x * 256 + threadIdx.x;
    if (i < M) dinv[i] = rsqrtf((float)cnt[i] + 1.0f);   // +1 self-loop
}

// GEMM  out[m, :] = (X[m, :] @ W) * dinv[m] (+ bias).
// Block: 256 threads, TM=64 rows.  LDS: W[K][N] + X tile [TM][K].
template<int K, int N>
__global__ __launch_bounds__(256)
void gemm_scale(const float* __restrict__ X, const float* __restrict__ W,
                const float* __restrict__ dinv, const float* __restrict__ bias,
                float* __restrict__ out, int M)
{
    constexpr int TM  = 64;
    constexpr int QPR = K / 4;      // float4 quads per X row
    __shared__ float Ws[K * N];
    __shared__ float Xs[TM * K];

    const int tid  = threadIdx.x;
    const int row0 = blockIdx.x * TM;

    for (int i = tid; i < K * N / 4; i += 256) {
        float4 v = reinterpret_cast<const float4*>(W)[i];
        *reinterpret_cast<float4*>(&Ws[i * 4]) = v;
    }
    for (int i = tid; i < TM * QPR; i += 256) {
        int r = i / QPR, q = i - r * QPR;
        int gr = row0 + r;
        float4 v = make_float4(0.f, 0.f, 0.f, 0.f);
        if (gr < M) v = reinterpret_cast<const float4*>(X)[(size_t)gr * QPR + q];
        *reinterpret_cast<float4*>(&Xs[r * K + q * 4]) = v;
    }
    __syncthreads();

    constexpr int CG  = N / 4;          // column groups (4 cols each)
    constexpr int RPT = N / 16;         // rows per thread (4 or 8)
    const int c0 = (tid % CG) * 4;
    const int r0 = (tid / CG) * RPT;

    float a[RPT][4];
    #pragma unroll
    for (int rr = 0; rr < RPT; ++rr) {
        a[rr][0] = 0.f; a[rr][1] = 0.f; a[rr][2] = 0.f; a[rr][3] = 0.f;
    }

    #pragma unroll 4
    for (int k = 0; k < K; ++k) {
        const float4 wv = *reinterpret_cast<const float4*>(&Ws[k * N + c0]);
        #pragma unroll
        for (int rr = 0; rr < RPT; ++rr) {
            const float xv = Xs[(r0 + rr) * K + k];
            a[rr][0] += xv * wv.x;
            a[rr][1] += xv * wv.y;
            a[rr][2] += xv * wv.z;
            a[rr][3] += xv * wv.w;
        }
    }

    float4 bv = make_float4(0.f, 0.f, 0.f, 0.f);
    if (bias) bv = *reinterpret_cast<const float4*>(&bias[c0]);

    #pragma unroll
    for (int rr = 0; rr < RPT; ++rr) {
        const int gr = row0 + r0 + rr;
        if (gr < M) {
            const float d = dinv[gr];
            float4 v;
            v.x = a[rr][0] * d + bv.x; v.y = a[rr][1] * d + bv.y;
            v.z = a[rr][2] * d + bv.z; v.w = a[rr][3] * d + bv.w;
            *reinterpret_cast<float4*>(&out[(size_t)gr * N + c0]) = v;
        }
    }
}

// Wave-per-node gather aggregation over 64-dim rows (1 float/lane).
//  PRE=false:  out[n] = dinv[n] * (hs[n] + sum_j hs[csr[n][j]]) + bias
//  PRE=true:   out[n] = hs[n]*dinv[n] + sum_j hs[csr[n][j]]*dinv[csr[n][j]]
// Edge-index loads are wave-uniform (n pinned to SGPR via readfirstlane) ->
// scalar loads; dinv[src] in the PRE path is likewise a scalar load from the
// L2-resident 400KB dinv array. Gathers are coalesced 256B per wave.
template<bool PRE>
__global__ __launch_bounds__(256)
void gcn_agg(const float* __restrict__ hs, const int* __restrict__ csr,
             const int* __restrict__ cnt, const float* __restrict__ dinv,
             const float* __restrict__ bias, float* __restrict__ out,
             int M, int cap)
{
    const int lane = threadIdx.x & 63;
    int n = (blockIdx.x * 256 + threadIdx.x) >> 6;
    if (n >= M) return;
    n = __builtin_amdgcn_readfirstlane(n);
    int deg = cnt[n];
    if (deg > cap) deg = cap;
    const int* __restrict__ lst = csr + (size_t)n * cap;
    const float dv = dinv[n];

    float acc = hs[(size_t)n * 64 + lane];
    if constexpr (PRE) acc *= dv;

    int j = 0;
    for (; j + 8 <= deg; j += 8) {
        const int s0 = lst[j],     s1 = lst[j + 1], s2 = lst[j + 2], s3 = lst[j + 3];
        const int s4 = lst[j + 4], s5 = lst[j + 5], s6 = lst[j + 6], s7 = lst[j + 7];
        float v0 = hs[(size_t)s0 * 64 + lane];
        float v1 = hs[(size_t)s1 * 64 + lane];
        float v2 = hs[(size_t)s2 * 64 + lane];
        float v3 = hs[(size_t)s3 * 64 + lane];
        float v4 = hs[(size_t)s4 * 64 + lane];
        float v5 = hs[(size_t)s5 * 64 + lane];
        float v6 = hs[(size_t)s6 * 64 + lane];
        float v7 = hs[(size_t)s7 * 64 + lane];
        if constexpr (PRE) {
            v0 *= dinv[s0]; v1 *= dinv[s1]; v2 *= dinv[s2]; v3 *= dinv[s3];
            v4 *= dinv[s4]; v5 *= dinv[s5]; v6 *= dinv[s6]; v7 *= dinv[s7];
        }
        acc += ((v0 + v1) + (v2 + v3)) + ((v4 + v5) + (v6 + v7));
    }
    for (; j + 4 <= deg; j += 4) {
        const int s0 = lst[j], s1 = lst[j + 1], s2 = lst[j + 2], s3 = lst[j + 3];
        float v0 = hs[(size_t)s0 * 64 + lane];
        float v1 = hs[(size_t)s1 * 64 + lane];
        float v2 = hs[(size_t)s2 * 64 + lane];
        float v3 = hs[(size_t)s3 * 64 + lane];
        if constexpr (PRE) {
            v0 *= dinv[s0]; v1 *= dinv[s1]; v2 *= dinv[s2]; v3 *= dinv[s3];
        }
        acc += (v0 + v1) + (v2 + v3);
    }
    for (; j < deg; ++j) {
        const int s = lst[j];
        float v = hs[(size_t)s * 64 + lane];
        if constexpr (PRE) v *= dinv[s];
        acc += v;
    }

    if constexpr (PRE) {
        out[(size_t)n * 64 + lane] = acc;
    } else {
        out[(size_t)n * 64 + lane] = acc * dv + bias[lane];
    }
}

extern "C" void kernel_launch(void* const* d_in, const int* in_sizes, int n_in,
                              void* d_out, int out_size, void* d_ws, size_t ws_size,
                              hipStream_t stream)
{
    const float* x    = (const float*)d_in[0];   // [M,128]
    const int*   ei   = (const int*)  d_in[1];   // [2,E]
    const float* Wenc = (const float*)d_in[2];   // [128,64]
    const float* benc = (const float*)d_in[3];   // [64]
    const float* Wdec = (const float*)d_in[4];   // [64,128]
    const float* bdec = (const float*)d_in[5];   // [128]

    const int M = in_sizes[0] / 128;             // 100000
    const int E = in_sizes[1] / 2;               // 1600000
    const int* src  = ei;
    const int* dstv = ei + E;

    float* emb   = (float*)d_out;                       // [M,64]
    float* recon = (float*)d_out + (size_t)M * 64;      // [M,128]

    // workspace layout
    float* hs1    = (float*)d_ws;                        // M*64 f32 (layer-1 pre-agg)
    float* agg2   = (float*)d_ws + (size_t)M * 64;       // M*64 f32 (layer-2 aggregated)
    int*   cursor = (int*)d_ws + (size_t)M * 128;        // M ints (count per dst)
    float* dinv   = (float*)((int*)d_ws + (size_t)M * 129);
    int*   csr    = (int*)d_ws + (size_t)M * 130;        // M*cap ints

    const size_t used = (size_t)M * 130 * 4;
    int cap = 64;                                        // Poisson(16): P(deg>64) ~ 1e-50
    const size_t avail = (ws_size > used) ? (ws_size - used) / ((size_t)M * 4) : 0;
    if ((size_t)cap > avail) cap = (int)avail;

    hipMemsetAsync(cursor, 0, (size_t)M * sizeof(int), stream);

    // 8 owner groups x edge windows of 1024 (4 edges/thread, int4 dst loads)
    const int chunks = (E + 1023) / 1024;
    bucket_kernel<<<chunks * 8, 256, 0, stream>>>(src, dstv, E, cursor, csr, cap);
    dinv_kernel<<<(M + 255) / 256, 256, 0, stream>>>(cursor, dinv, M);

    const int aggBlocks = (M + 3) / 4;   // 4 waves (nodes) per 256-thread block

    // ---- layer 1: encode 128 -> 64 ----
    gemm_scale<128, 64><<<(M + 63) / 64, 256, 0, stream>>>(x, Wenc, dinv, nullptr, hs1, M);
    gcn_agg<false><<<aggBlocks, 256, 0, stream>>>(hs1, csr, cursor, dinv, benc, emb, M, cap);

    // ---- layer 2: decode 64 -> 128 (aggregate in 64-dim, then GEMM) ----
    gcn_agg<true><<<aggBlocks, 256, 0, stream>>>(emb, csr, cursor, dinv, nullptr, agg2, M, cap);
    gemm_scale<64, 128><<<(M + 63) / 64, 256, 0, stream>>>(agg2, Wdec, dinv, bdec, recon, M);
}

// Round 3
// 341.800 us; speedup vs baseline: 1.4269x; 1.1132x over previous
//
#include <hip/hip_runtime.h>

// ---------------------------------------------------------------------------
// localAE: two GCNConv layers (128->64 encode, 64->128 decode), N=100000,
// E=1.6M.  out[n] = dinv[n] * (hs[n] + sum_{e: dst==n} hs[src_e]) + b
// where hs = (X @ W) * dinv[row],  dinv = rsqrt(1 + indegree).
//
// Round 5: two-phase CSR build. Round-3/4 bucket_kernel did one returning
// device atomic per edge; on gfx950 device-scope RMW bypasses the per-XCD L2
// to the fabric (L2s non-coherent), so 1.6M atomics = ~50MB fetch + ~50MB
// write of fabric RMW traffic and a ~21G atomics/s throughput wall (77us).
// Now: P1 partitions edges into 782 buckets of 128 nodes (LDS histogram,
// ONE global atomic per block x bucket = ~306k device atomics, 5x fewer);
// P2 builds CSR per bucket with per-node cursors in LDS (1.6M LDS atomics,
// zero fabric RMW) and CSR writes confined to a 32KB region that merges in
// L2. dinv fused into P2. No correctness dependence on XCD mapping.
// ---------------------------------------------------------------------------

#define BSHIFT 7                      // 128 nodes per bucket
#define BNODES (1 << BSHIFT)
#define NB_LDS 1024                   // LDS histogram capacity (NB <= 1024)

// P1: partition edges into buckets by dst>>BSHIFT, packed (src<<BSHIFT)|dloc.
__global__ __launch_bounds__(1024)
void part_kernel(const int* __restrict__ src, const int* __restrict__ dst,
                 int E, int NB, int* __restrict__ gcur, int* __restrict__ gbuf,
                 int BSTRIDE)
{
    __shared__ int hist[NB_LDS];
    __shared__ int bbase[NB_LDS];
    const int tid = threadIdx.x;
    for (int i = tid; i < NB; i += 1024) hist[i] = 0;
    __syncthreads();

    const int base = (blockIdx.x * 1024 + tid) * 4;
    int bk[4], lp[4], pk[4];
    int nv = 0;
    if (base + 4 <= E) {
        const int4 d4 = *reinterpret_cast<const int4*>(dst + base);
        const int4 s4 = *reinterpret_cast<const int4*>(src + base);
        nv = 4;
        #pragma unroll
        for (int k = 0; k < 4; ++k) {
            const int d = (&d4.x)[k];
            bk[k] = d >> BSHIFT;
            pk[k] = ((&s4.x)[k] << BSHIFT) | (d & (BNODES - 1));
            lp[k] = atomicAdd(&hist[bk[k]], 1);
        }
    } else {
        for (int k = 0; base + k < E && k < 4; ++k) {
            const int d = dst[base + k];
            bk[nv] = d >> BSHIFT;
            pk[nv] = (src[base + k] << BSHIFT) | (d & (BNODES - 1));
            lp[nv] = atomicAdd(&hist[bk[nv]], 1);
            ++nv;
        }
    }
    __syncthreads();
    for (int i = tid; i < NB; i += 1024) {
        const int c = hist[i];
        bbase[i] = c ? atomicAdd(&gcur[i], c) : 0;   // one device atomic per (block,bucket)
    }
    __syncthreads();
    for (int k = 0; k < nv; ++k) {
        const int pos = bbase[bk[k]] + lp[k];
        if (pos < BSTRIDE) gbuf[(size_t)bk[k] * BSTRIDE + pos] = pk[k];
    }
}

// P2: per bucket (128 nodes), slot edges into CSR rows via LDS cursors.
// Also emits per-node degree count and dinv (fused).
__global__ __launch_bounds__(256)
void csr_kernel(const int* __restrict__ gcur, const int* __restrict__ gbuf,
                int BSTRIDE, int* __restrict__ csr, int cap,
                int* __restrict__ cnt, float* __restrict__ dinv, int M)
{
    __shared__ int cur[BNODES];
    const int tid = threadIdx.x;
    const int b   = blockIdx.x;
    if (tid < BNODES) cur[tid] = 0;
    __syncthreads();

    int nb = gcur[b];
    if (nb > BSTRIDE) nb = BSTRIDE;
    const int* __restrict__ buf = gbuf + (size_t)b * BSTRIDE;
    const int n0 = b << BSHIFT;

    for (int i = tid; i < nb; i += 256) {
        const int p = buf[i];
        const int d = p & (BNODES - 1);
        const int s = p >> BSHIFT;
        const int lpos = atomicAdd(&cur[d], 1);        // LDS atomic
        if (lpos < cap) csr[(size_t)(n0 + d) * cap + lpos] = s;
    }
    __syncthreads();
    const int n = n0 + tid;
    if (tid < BNODES && n < M) {
        const int c = cur[tid];
        cnt[n]  = c;                                   // true in-degree
        dinv[n] = rsqrtf((float)c + 1.0f);             // +1 self-loop
    }
}

// GEMM  out[m, :] = (X[m, :] @ W) * dinv[m] (+ bias).
// Block: 256 threads, TM=64 rows.  LDS: W[K][N] + X tile [TM][K].
template<int K, int N>
__global__ __launch_bounds__(256)
void gemm_scale(const float* __restrict__ X, const float* __restrict__ W,
                const float* __restrict__ dinv, const float* __restrict__ bias,
                float* __restrict__ out, int M)
{
    constexpr int TM  = 64;
    constexpr int QPR = K / 4;      // float4 quads per X row
    __shared__ float Ws[K * N];
    __shared__ float Xs[TM * K];

    const int tid  = threadIdx.x;
    const int row0 = blockIdx.x * TM;

    for (int i = tid; i < K * N / 4; i += 256) {
        float4 v = reinterpret_cast<const float4*>(W)[i];
        *reinterpret_cast<float4*>(&Ws[i * 4]) = v;
    }
    for (int i = tid; i < TM * QPR; i += 256) {
        int r = i / QPR, q = i - r * QPR;
        int gr = row0 + r;
        float4 v = make_float4(0.f, 0.f, 0.f, 0.f);
        if (gr < M) v = reinterpret_cast<const float4*>(X)[(size_t)gr * QPR + q];
        *reinterpret_cast<float4*>(&Xs[r * K + q * 4]) = v;
    }
    __syncthreads();

    constexpr int CG  = N / 4;          // column groups (4 cols each)
    constexpr int RPT = N / 16;         // rows per thread (4 or 8)
    const int c0 = (tid % CG) * 4;
    const int r0 = (tid / CG) * RPT;

    float a[RPT][4];
    #pragma unroll
    for (int rr = 0; rr < RPT; ++rr) {
        a[rr][0] = 0.f; a[rr][1] = 0.f; a[rr][2] = 0.f; a[rr][3] = 0.f;
    }

    #pragma unroll 4
    for (int k = 0; k < K; ++k) {
        const float4 wv = *reinterpret_cast<const float4*>(&Ws[k * N + c0]);
        #pragma unroll
        for (int rr = 0; rr < RPT; ++rr) {
            const float xv = Xs[(r0 + rr) * K + k];
            a[rr][0] += xv * wv.x;
            a[rr][1] += xv * wv.y;
            a[rr][2] += xv * wv.z;
            a[rr][3] += xv * wv.w;
        }
    }

    float4 bv = make_float4(0.f, 0.f, 0.f, 0.f);
    if (bias) bv = *reinterpret_cast<const float4*>(&bias[c0]);

    #pragma unroll
    for (int rr = 0; rr < RPT; ++rr) {
        const int gr = row0 + r0 + rr;
        if (gr < M) {
            const float d = dinv[gr];
            float4 v;
            v.x = a[rr][0] * d + bv.x; v.y = a[rr][1] * d + bv.y;
            v.z = a[rr][2] * d + bv.z; v.w = a[rr][3] * d + bv.w;
            *reinterpret_cast<float4*>(&out[(size_t)gr * N + c0]) = v;
        }
    }
}

// Wave-per-node gather aggregation over 64-dim rows (1 float/lane).
//  PRE=false:  out[n] = dinv[n] * (hs[n] + sum_j hs[csr[n][j]]) + bias
//  PRE=true:   out[n] = hs[n]*dinv[n] + sum_j hs[csr[n][j]]*dinv[csr[n][j]]
// Edge-index loads are wave-uniform (n pinned to SGPR via readfirstlane) ->
// scalar loads. Gathers are coalesced 256B/wave; unroll 16 matches avg deg
// so a typical node issues all its gathers in one latency batch.
template<bool PRE>
__global__ __launch_bounds__(256)
void gcn_agg(const float* __restrict__ hs, const int* __restrict__ csr,
             const int* __restrict__ cnt, const float* __restrict__ dinv,
             const float* __restrict__ bias, float* __restrict__ out,
             int M, int cap)
{
    const int lane = threadIdx.x & 63;
    int n = (blockIdx.x * 256 + threadIdx.x) >> 6;
    if (n >= M) return;
    n = __builtin_amdgcn_readfirstlane(n);
    int deg = cnt[n];
    if (deg > cap) deg = cap;
    const int* __restrict__ lst = csr + (size_t)n * cap;
    const float dv = dinv[n];

    float acc = hs[(size_t)n * 64 + lane];
    if constexpr (PRE) acc *= dv;

    int j = 0;
    for (; j + 16 <= deg; j += 16) {
        int   s[16];
        float v[16];
        #pragma unroll
        for (int k = 0; k < 16; ++k) s[k] = lst[j + k];
        #pragma unroll
        for (int k = 0; k < 16; ++k) v[k] = hs[(size_t)s[k] * 64 + lane];
        if constexpr (PRE) {
            #pragma unroll
            for (int k = 0; k < 16; ++k) v[k] *= dinv[s[k]];
        }
        float t = 0.f;
        #pragma unroll
        for (int k = 0; k < 16; ++k) t += v[k];
        acc += t;
    }
    for (; j + 4 <= deg; j += 4) {
        const int s0 = lst[j], s1 = lst[j + 1], s2 = lst[j + 2], s3 = lst[j + 3];
        float v0 = hs[(size_t)s0 * 64 + lane];
        float v1 = hs[(size_t)s1 * 64 + lane];
        float v2 = hs[(size_t)s2 * 64 + lane];
        float v3 = hs[(size_t)s3 * 64 + lane];
        if constexpr (PRE) {
            v0 *= dinv[s0]; v1 *= dinv[s1]; v2 *= dinv[s2]; v3 *= dinv[s3];
        }
        acc += (v0 + v1) + (v2 + v3);
    }
    for (; j < deg; ++j) {
        const int s = lst[j];
        float v = hs[(size_t)s * 64 + lane];
        if constexpr (PRE) v *= dinv[s];
        acc += v;
    }

    if constexpr (PRE) {
        out[(size_t)n * 64 + lane] = acc;
    } else {
        out[(size_t)n * 64 + lane] = acc * dv + bias[lane];
    }
}

extern "C" void kernel_launch(void* const* d_in, const int* in_sizes, int n_in,
                              void* d_out, int out_size, void* d_ws, size_t ws_size,
                              hipStream_t stream)
{
    const float* x    = (const float*)d_in[0];   // [M,128]
    const int*   ei   = (const int*)  d_in[1];   // [2,E]
    const float* Wenc = (const float*)d_in[2];   // [128,64]
    const float* benc = (const float*)d_in[3];   // [64]
    const float* Wdec = (const float*)d_in[4];   // [64,128]
    const float* bdec = (const float*)d_in[5];   // [128]

    const int M = in_sizes[0] / 128;             // 100000
    const int E = in_sizes[1] / 2;               // 1600000
    const int* src  = ei;
    const int* dstv = ei + E;

    float* emb   = (float*)d_out;                       // [M,64]
    float* recon = (float*)d_out + (size_t)M * 64;      // [M,128]

    const int NB      = (M + BNODES - 1) >> BSHIFT;     // 782 buckets
    const int BSTRIDE = 3072;                           // mean 2046, +22 sigma

    // workspace layout (ints):
    //   [0,        M*64)   hs1 (layer-1 pre-agg, f32)
    //   [M*64,     M*128)  gbuf (P1 output) UNION agg2 (layer-2 agg, f32)
    //   [M*128,    M*129)  cnt  (in-degree)
    //   [M*129,    M*130)  dinv (f32)
    //   [M*130,    +1024)  gcur (bucket counters, padded)
    //   [M*130+1024, ...)  csr  (M*cap)
    float* hs1  = (float*)d_ws;
    int*   gbuf = (int*)d_ws + (size_t)M * 64;
    float* agg2 = (float*)d_ws + (size_t)M * 64;
    int*   cnt  = (int*)d_ws + (size_t)M * 128;
    float* dinv = (float*)((int*)d_ws + (size_t)M * 129);
    int*   gcur = (int*)d_ws + (size_t)M * 130;
    int*   csr  = (int*)d_ws + (size_t)M * 130 + 1024;

    const size_t used = ((size_t)M * 130 + 1024) * 4;
    int cap = 64;                                        // Poisson(16): P(deg>64) ~ 1e-50
    const size_t avail = (ws_size > used) ? (ws_size - used) / ((size_t)M * 4) : 0;
    if ((size_t)cap > avail) cap = (int)avail;

    hipMemsetAsync(gcur, 0, (size_t)NB * sizeof(int), stream);

    // ---- CSR build: partition (4096 edges/block) then per-bucket slotting ----
    part_kernel<<<(E + 4095) / 4096, 1024, 0, stream>>>(src, dstv, E, NB, gcur, gbuf, BSTRIDE);
    csr_kernel<<<NB, 256, 0, stream>>>(gcur, gbuf, BSTRIDE, csr, cap, cnt, dinv, M);

    const int aggBlocks = (M + 3) / 4;   // 4 waves (nodes) per 256-thread block

    // ---- layer 1: encode 128 -> 64 ----
    gemm_scale<128, 64><<<(M + 63) / 64, 256, 0, stream>>>(x, Wenc, dinv, nullptr, hs1, M);
    gcn_agg<false><<<aggBlocks, 256, 0, stream>>>(hs1, csr, cnt, dinv, benc, emb, M, cap);

    // ---- layer 2: decode 64 -> 128 (aggregate in 64-dim, then GEMM) ----
    gcn_agg<true><<<aggBlocks, 256, 0, stream>>>(emb, csr, cnt, dinv, nullptr, agg2, M, cap);
    gemm_scale<64, 128><<<(M + 63) / 64, 256, 0, stream>>>(agg2, Wdec, dinv, bdec, recon, M);
}

// Round 4
// 298.372 us; speedup vs baseline: 1.6346x; 1.1456x over previous
//
#include <hip/hip_runtime.h>
#include <hip/hip_fp16.h>

// ---------------------------------------------------------------------------
// localAE: two GCNConv layers (128->64 encode, 64->128 decode), N=100000,
// E=1.6M.  out[n] = dinv[n] * (hs[n] + sum_{e: dst==n} hs[src_e]) + b
// where hs = (X @ W) * dinv[row],  dinv = rsqrt(1 + indegree).
//
// Round 6: fp16 gather operands. The two agg passes were at the compulsory-
// miss floor for a 25.6MB f32 operand (FETCH 202MB = 8 XCDs x ~whole array;
// random graph -> no locality to recover). Halve bytes instead: gemm1 emits
// hs1 in fp16 (one 128B line per wave-gather instead of two), agg1's
// epilogue emits g[n]=emb[n]*dinv[n] in fp16 for agg2 (also kills the
// dinv[src] scalar loads). Accumulation stays f32; only the stored operand
// is rounded (adds ~e-4 error, an order below the 0.0039 structural absmax).
// ---------------------------------------------------------------------------

#define BSHIFT 7                      // 128 nodes per bucket
#define BNODES (1 << BSHIFT)
#define NB_LDS 1024                   // LDS histogram capacity (NB <= 1024)

// P1: partition edges into buckets by dst>>BSHIFT, packed (src<<BSHIFT)|dloc.
// One global atomic per (block,bucket) instead of per edge (fabric-RMW wall).
__global__ __launch_bounds__(1024)
void part_kernel(const int* __restrict__ src, const int* __restrict__ dst,
                 int E, int NB, int* __restrict__ gcur, int* __restrict__ gbuf,
                 int BSTRIDE)
{
    __shared__ int hist[NB_LDS];
    __shared__ int bbase[NB_LDS];
    const int tid = threadIdx.x;
    for (int i = tid; i < NB; i += 1024) hist[i] = 0;
    __syncthreads();

    const int base = (blockIdx.x * 1024 + tid) * 4;
    int bk[4], lp[4], pk[4];
    int nv = 0;
    if (base + 4 <= E) {
        const int4 d4 = *reinterpret_cast<const int4*>(dst + base);
        const int4 s4 = *reinterpret_cast<const int4*>(src + base);
        nv = 4;
        #pragma unroll
        for (int k = 0; k < 4; ++k) {
            const int d = (&d4.x)[k];
            bk[k] = d >> BSHIFT;
            pk[k] = ((&s4.x)[k] << BSHIFT) | (d & (BNODES - 1));
            lp[k] = atomicAdd(&hist[bk[k]], 1);
        }
    } else {
        for (int k = 0; base + k < E && k < 4; ++k) {
            const int d = dst[base + k];
            bk[nv] = d >> BSHIFT;
            pk[nv] = (src[base + k] << BSHIFT) | (d & (BNODES - 1));
            lp[nv] = atomicAdd(&hist[bk[nv]], 1);
            ++nv;
        }
    }
    __syncthreads();
    for (int i = tid; i < NB; i += 1024) {
        const int c = hist[i];
        bbase[i] = c ? atomicAdd(&gcur[i], c) : 0;   // one device atomic per (block,bucket)
    }
    __syncthreads();
    for (int k = 0; k < nv; ++k) {
        const int pos = bbase[bk[k]] + lp[k];
        if (pos < BSTRIDE) gbuf[(size_t)bk[k] * BSTRIDE + pos] = pk[k];
    }
}

// P2: per bucket (128 nodes), slot edges into CSR rows via LDS cursors
// (zero fabric RMW); CSR writes confined to a 32KB region -> merge in L2.
// Degree count + dinv fused.
__global__ __launch_bounds__(256)
void csr_kernel(const int* __restrict__ gcur, const int* __restrict__ gbuf,
                int BSTRIDE, int* __restrict__ csr, int cap,
                int* __restrict__ cnt, float* __restrict__ dinv, int M)
{
    __shared__ int cur[BNODES];
    const int tid = threadIdx.x;
    const int b   = blockIdx.x;
    if (tid < BNODES) cur[tid] = 0;
    __syncthreads();

    int nb = gcur[b];
    if (nb > BSTRIDE) nb = BSTRIDE;
    const int* __restrict__ buf = gbuf + (size_t)b * BSTRIDE;
    const int n0 = b << BSHIFT;

    for (int i = tid; i < nb; i += 256) {
        const int p = buf[i];
        const int d = p & (BNODES - 1);
        const int s = p >> BSHIFT;
        const int lpos = atomicAdd(&cur[d], 1);        // LDS atomic
        if (lpos < cap) csr[(size_t)(n0 + d) * cap + lpos] = s;
    }
    __syncthreads();
    const int n = n0 + tid;
    if (tid < BNODES && n < M) {
        const int c = cur[tid];
        cnt[n]  = c;                                   // true in-degree
        dinv[n] = rsqrtf((float)c + 1.0f);             // +1 self-loop
    }
}

// GEMM  out[m, :] = (X[m, :] @ W) * dinv[m] (+ bias).
// HOUT: emit fp16 (packed 4 halves / 8B store) instead of f32.
// Block: 256 threads, TM=64 rows.  LDS: W[K][N] + X tile [TM][K].
template<int K, int N, bool HOUT>
__global__ __launch_bounds__(256)
void gemm_scale(const float* __restrict__ X, const float* __restrict__ W,
                const float* __restrict__ dinv, const float* __restrict__ bias,
                float* __restrict__ out, __half* __restrict__ outh, int M)
{
    constexpr int TM  = 64;
    constexpr int QPR = K / 4;      // float4 quads per X row
    __shared__ float Ws[K * N];
    __shared__ float Xs[TM * K];

    const int tid  = threadIdx.x;
    const int row0 = blockIdx.x * TM;

    for (int i = tid; i < K * N / 4; i += 256) {
        float4 v = reinterpret_cast<const float4*>(W)[i];
        *reinterpret_cast<float4*>(&Ws[i * 4]) = v;
    }
    for (int i = tid; i < TM * QPR; i += 256) {
        int r = i / QPR, q = i - r * QPR;
        int gr = row0 + r;
        float4 v = make_float4(0.f, 0.f, 0.f, 0.f);
        if (gr < M) v = reinterpret_cast<const float4*>(X)[(size_t)gr * QPR + q];
        *reinterpret_cast<float4*>(&Xs[r * K + q * 4]) = v;
    }
    __syncthreads();

    constexpr int CG  = N / 4;          // column groups (4 cols each)
    constexpr int RPT = N / 16;         // rows per thread (4 or 8)
    const int c0 = (tid % CG) * 4;
    const int r0 = (tid / CG) * RPT;

    float a[RPT][4];
    #pragma unroll
    for (int rr = 0; rr < RPT; ++rr) {
        a[rr][0] = 0.f; a[rr][1] = 0.f; a[rr][2] = 0.f; a[rr][3] = 0.f;
    }

    #pragma unroll 4
    for (int k = 0; k < K; ++k) {
        const float4 wv = *reinterpret_cast<const float4*>(&Ws[k * N + c0]);
        #pragma unroll
        for (int rr = 0; rr < RPT; ++rr) {
            const float xv = Xs[(r0 + rr) * K + k];
            a[rr][0] += xv * wv.x;
            a[rr][1] += xv * wv.y;
            a[rr][2] += xv * wv.z;
            a[rr][3] += xv * wv.w;
        }
    }

    float4 bv = make_float4(0.f, 0.f, 0.f, 0.f);
    if (bias) bv = *reinterpret_cast<const float4*>(&bias[c0]);

    #pragma unroll
    for (int rr = 0; rr < RPT; ++rr) {
        const int gr = row0 + r0 + rr;
        if (gr < M) {
            const float d = dinv[gr];
            float4 v;
            v.x = a[rr][0] * d + bv.x; v.y = a[rr][1] * d + bv.y;
            v.z = a[rr][2] * d + bv.z; v.w = a[rr][3] * d + bv.w;
            if constexpr (HOUT) {
                union { __half2 h2[2]; uint2 u; } pk;
                pk.h2[0] = __floats2half2_rn(v.x, v.y);
                pk.h2[1] = __floats2half2_rn(v.z, v.w);
                *reinterpret_cast<uint2*>(&outh[(size_t)gr * N + c0]) = pk.u;
            } else {
                *reinterpret_cast<float4*>(&out[(size_t)gr * N + c0]) = v;
            }
        }
    }
}

// Wave-per-node gather aggregation over 64-dim fp16 rows (1 half/lane,
// 128B/wave-gather = one cache line). f32 accumulate. Edge-index loads are
// wave-uniform (n pinned to SGPR) -> scalar loads. Unroll 16 ~ avg degree.
//  FIRST=true : hsh = hs1;  emb[n] = acc*dinv[n] + bias (f32 out)
//               and ghalf[n] = emb[n]*dinv[n] (fp16 out, feeds agg2)
//  FIRST=false: hsh = g;    out[n] = acc (f32, feeds decode GEMM)
template<bool FIRST>
__global__ __launch_bounds__(256)
void gcn_agg(const __half* __restrict__ hsh, const int* __restrict__ csr,
             const int* __restrict__ cnt, const float* __restrict__ dinv,
             const float* __restrict__ bias, float* __restrict__ outf,
             __half* __restrict__ outh, int M, int cap)
{
    const int lane = threadIdx.x & 63;
    int n = (blockIdx.x * 256 + threadIdx.x) >> 6;
    if (n >= M) return;
    n = __builtin_amdgcn_readfirstlane(n);
    int deg = cnt[n];
    if (deg > cap) deg = cap;
    const int* __restrict__ lst = csr + (size_t)n * cap;

    float acc = __half2float(hsh[(size_t)n * 64 + lane]);

    int j = 0;
    for (; j + 16 <= deg; j += 16) {
        int   s[16];
        float v[16];
        #pragma unroll
        for (int k = 0; k < 16; ++k) s[k] = lst[j + k];
        #pragma unroll
        for (int k = 0; k < 16; ++k) v[k] = __half2float(hsh[(size_t)s[k] * 64 + lane]);
        float t = 0.f;
        #pragma unroll
        for (int k = 0; k < 16; ++k) t += v[k];
        acc += t;
    }
    for (; j + 4 <= deg; j += 4) {
        const int s0 = lst[j], s1 = lst[j + 1], s2 = lst[j + 2], s3 = lst[j + 3];
        const float v0 = __half2float(hsh[(size_t)s0 * 64 + lane]);
        const float v1 = __half2float(hsh[(size_t)s1 * 64 + lane]);
        const float v2 = __half2float(hsh[(size_t)s2 * 64 + lane]);
        const float v3 = __half2float(hsh[(size_t)s3 * 64 + lane]);
        acc += (v0 + v1) + (v2 + v3);
    }
    for (; j < deg; ++j) acc += __half2float(hsh[(size_t)lst[j] * 64 + lane]);

    if constexpr (FIRST) {
        const float dv = dinv[n];
        const float e  = acc * dv + bias[lane];
        outf[(size_t)n * 64 + lane] = e;                       // emb (f32 output)
        outh[(size_t)n * 64 + lane] = __float2half_rn(e * dv); // g = emb*dinv (fp16)
    } else {
        outf[(size_t)n * 64 + lane] = acc;                     // agg2 (f32)
    }
}

extern "C" void kernel_launch(void* const* d_in, const int* in_sizes, int n_in,
                              void* d_out, int out_size, void* d_ws, size_t ws_size,
                              hipStream_t stream)
{
    const float* x    = (const float*)d_in[0];   // [M,128]
    const int*   ei   = (const int*)  d_in[1];   // [2,E]
    const float* Wenc = (const float*)d_in[2];   // [128,64]
    const float* benc = (const float*)d_in[3];   // [64]
    const float* Wdec = (const float*)d_in[4];   // [64,128]
    const float* bdec = (const float*)d_in[5];   // [128]

    const int M = in_sizes[0] / 128;             // 100000
    const int E = in_sizes[1] / 2;               // 1600000
    const int* src  = ei;
    const int* dstv = ei + E;

    float* emb   = (float*)d_out;                       // [M,64]
    float* recon = (float*)d_out + (size_t)M * 64;      // [M,128]

    const int NB      = (M + BNODES - 1) >> BSHIFT;     // 782 buckets
    const int BSTRIDE = 3072;                           // mean 2046, +22 sigma

    // workspace layout (int units):
    //   [0,       M*32)    hs1h  (layer-1 pre-agg, fp16, M*64 halves)
    //   [M*32,    M*64)    ghalf (g = emb*dinv, fp16, M*64 halves)
    //   [M*64,    M*128)   gbuf (P1 output, 2.4M ints) UNION agg2 (f32 M*64)
    //   [M*128,   M*129)   cnt  (in-degree)
    //   [M*129,   M*130)   dinv (f32)
    //   [M*130,   +1024)   gcur (bucket counters, padded)
    //   [M*130+1024, ...)  csr  (M*cap)
    __half* hs1h  = (__half*)d_ws;
    __half* ghalf = (__half*)((int*)d_ws + (size_t)M * 32);
    int*    gbuf  = (int*)d_ws + (size_t)M * 64;
    float*  agg2  = (float*)((int*)d_ws + (size_t)M * 64);
    int*    cnt   = (int*)d_ws + (size_t)M * 128;
    float*  dinv  = (float*)((int*)d_ws + (size_t)M * 129);
    int*    gcur  = (int*)d_ws + (size_t)M * 130;
    int*    csr   = (int*)d_ws + (size_t)M * 130 + 1024;

    const size_t used = ((size_t)M * 130 + 1024) * 4;
    int cap = 64;                                        // Poisson(16): P(deg>64) ~ 1e-50
    const size_t avail = (ws_size > used) ? (ws_size - used) / ((size_t)M * 4) : 0;
    if ((size_t)cap > avail) cap = (int)avail;

    hipMemsetAsync(gcur, 0, 1024 * sizeof(int), stream);

    // ---- CSR build: partition (4096 edges/block) then per-bucket slotting ----
    part_kernel<<<(E + 4095) / 4096, 1024, 0, stream>>>(src, dstv, E, NB, gcur, gbuf, BSTRIDE);
    csr_kernel<<<NB, 256, 0, stream>>>(gcur, gbuf, BSTRIDE, csr, cap, cnt, dinv, M);

    const int aggBlocks = (M + 3) / 4;   // 4 waves (nodes) per 256-thread block

    // ---- layer 1: encode 128 -> 64 ----
    gemm_scale<128, 64, true><<<(M + 63) / 64, 256, 0, stream>>>(
        x, Wenc, dinv, nullptr, nullptr, hs1h, M);
    gcn_agg<true><<<aggBlocks, 256, 0, stream>>>(
        hs1h, csr, cnt, dinv, benc, emb, ghalf, M, cap);

    // ---- layer 2: decode 64 -> 128 (aggregate in 64-dim, then GEMM) ----
    gcn_agg<false><<<aggBlocks, 256, 0, stream>>>(
        ghalf, csr, cnt, nullptr, nullptr, agg2, nullptr, M, cap);
    gemm_scale<64, 128, false><<<(M + 63) / 64, 256, 0, stream>>>(
        agg2, Wdec, dinv, bdec, recon, nullptr, M);
}

// Round 5
// 294.972 us; speedup vs baseline: 1.6534x; 1.0115x over previous
//
#include <hip/hip_runtime.h>
#include <hip/hip_fp16.h>

// ---------------------------------------------------------------------------
// localAE: two GCNConv layers (128->64 encode, 64->128 decode), N=100000,
// E=1.6M.  out[n] = dinv[n] * (hs[n] + sum_{e: dst==n} hs[src_e]) + b
// where hs = (X @ W) * dinv[row],  dinv = rsqrt(1 + indegree).
//
// Round 7: register-blocked GEMM. Old gemm_scale was LDS-issue bound
// (1 b128 + 4 conflicted b32 per 16 FMA, 64KB LDS -> 2 blocks/CU):
// 56us vs a 10.4us f32-VALU floor, VALUBusy 24%, 3.2M bank-conflict cycles.
// New gemm_rb: 8x8 outputs/thread, X read from GLOBAL through L1 (the 8
// col-group lanes of a wave issue the same address -> in-wave dedup; a 64B
// line covers 4 k-chunks -> L1 hits), only W in LDS (32KB, broadcast reads).
// Per k: 2 ds_read_b128 + amortized 2 global_dwordx4 for 64 FMAs -> VALU-
// bound. Pure f32, numerics unchanged.
// ---------------------------------------------------------------------------

#define BSHIFT 7                      // 128 nodes per bucket
#define BNODES (1 << BSHIFT)
#define NB_LDS 1024                   // LDS histogram capacity (NB <= 1024)

// P1: partition edges into buckets by dst>>BSHIFT, packed (src<<BSHIFT)|dloc.
// One global atomic per (block,bucket) instead of per edge (fabric-RMW wall).
__global__ __launch_bounds__(1024)
void part_kernel(const int* __restrict__ src, const int* __restrict__ dst,
                 int E, int NB, int* __restrict__ gcur, int* __restrict__ gbuf,
                 int BSTRIDE)
{
    __shared__ int hist[NB_LDS];
    __shared__ int bbase[NB_LDS];
    const int tid = threadIdx.x;
    for (int i = tid; i < NB; i += 1024) hist[i] = 0;
    __syncthreads();

    const int base = (blockIdx.x * 1024 + tid) * 4;
    int bk[4], lp[4], pk[4];
    int nv = 0;
    if (base + 4 <= E) {
        const int4 d4 = *reinterpret_cast<const int4*>(dst + base);
        const int4 s4 = *reinterpret_cast<const int4*>(src + base);
        nv = 4;
        #pragma unroll
        for (int k = 0; k < 4; ++k) {
            const int d = (&d4.x)[k];
            bk[k] = d >> BSHIFT;
            pk[k] = ((&s4.x)[k] << BSHIFT) | (d & (BNODES - 1));
            lp[k] = atomicAdd(&hist[bk[k]], 1);
        }
    } else {
        for (int k = 0; base + k < E && k < 4; ++k) {
            const int d = dst[base + k];
            bk[nv] = d >> BSHIFT;
            pk[nv] = (src[base + k] << BSHIFT) | (d & (BNODES - 1));
            lp[nv] = atomicAdd(&hist[bk[nv]], 1);
            ++nv;
        }
    }
    __syncthreads();
    for (int i = tid; i < NB; i += 1024) {
        const int c = hist[i];
        bbase[i] = c ? atomicAdd(&gcur[i], c) : 0;   // one device atomic per (block,bucket)
    }
    __syncthreads();
    for (int k = 0; k < nv; ++k) {
        const int pos = bbase[bk[k]] + lp[k];
        if (pos < BSTRIDE) gbuf[(size_t)bk[k] * BSTRIDE + pos] = pk[k];
    }
}

// P2: per bucket (128 nodes), slot edges into CSR rows via LDS cursors
// (zero fabric RMW); CSR writes confined to a 32KB region -> merge in L2.
// Degree count + dinv fused.
__global__ __launch_bounds__(256)
void csr_kernel(const int* __restrict__ gcur, const int* __restrict__ gbuf,
                int BSTRIDE, int* __restrict__ csr, int cap,
                int* __restrict__ cnt, float* __restrict__ dinv, int M)
{
    __shared__ int cur[BNODES];
    const int tid = threadIdx.x;
    const int b   = blockIdx.x;
    if (tid < BNODES) cur[tid] = 0;
    __syncthreads();

    int nb = gcur[b];
    if (nb > BSTRIDE) nb = BSTRIDE;
    const int* __restrict__ buf = gbuf + (size_t)b * BSTRIDE;
    const int n0 = b << BSHIFT;

    for (int i = tid; i < nb; i += 256) {
        const int p = buf[i];
        const int d = p & (BNODES - 1);
        const int s = p >> BSHIFT;
        const int lpos = atomicAdd(&cur[d], 1);        // LDS atomic
        if (lpos < cap) csr[(size_t)(n0 + d) * cap + lpos] = s;
    }
    __syncthreads();
    const int n = n0 + tid;
    if (tid < BNODES && n < M) {
        const int c = cur[tid];
        cnt[n]  = c;                                   // true in-degree
        dinv[n] = rsqrtf((float)c + 1.0f);             // +1 self-loop
    }
}

// Register-blocked GEMM: out[m,:] = (X[m,:] @ W) * dinv[m] (+ bias).
// 256 threads as CG col-groups x RG row-groups; each thread computes an
// 8-row x 8-col output tile. W staged in LDS (32KB, broadcast b128 reads);
// X read from global (wave dedups the CG same-address lanes; L1 covers the
// 4-k-chunk line reuse). HOUT: pack 8 halves -> one 16B store.
template<int K, int N, int CG, bool HOUT>
__global__ __launch_bounds__(256)
void gemm_rb(const float* __restrict__ X, const float* __restrict__ W,
             const float* __restrict__ dinv, const float* __restrict__ bias,
             float* __restrict__ out, __half* __restrict__ outh, int M)
{
    constexpr int RG = 256 / CG;
    constexpr int TM = RG * 8;
    __shared__ float Ws[K * N];

    const int tid = threadIdx.x;
    for (int i = tid; i < K * N / 4; i += 256)
        reinterpret_cast<float4*>(Ws)[i] = reinterpret_cast<const float4*>(W)[i];
    __syncthreads();

    const int cg   = tid % CG;
    const int rg   = tid / CG;
    const int c0   = cg * 8;
    const int row0 = blockIdx.x * TM + rg * 8;

    float acc[8][8];
    #pragma unroll
    for (int r = 0; r < 8; ++r)
        #pragma unroll
        for (int c = 0; c < 8; ++c) acc[r][c] = 0.f;

    const float* xp[8];
    #pragma unroll
    for (int r = 0; r < 8; ++r) {
        int rr = row0 + r;
        if (rr >= M) rr = M - 1;                  // clamp loads; stores guarded
        xp[r] = X + (size_t)rr * K;
    }

    for (int k = 0; k < K; k += 4) {
        float4 xv[8];
        #pragma unroll
        for (int r = 0; r < 8; ++r)
            xv[r] = *reinterpret_cast<const float4*>(xp[r] + k);

        #pragma unroll
        for (int kk = 0; kk < 4; ++kk) {
            const float4 w0 = *reinterpret_cast<const float4*>(&Ws[(k + kk) * N + c0]);
            const float4 w1 = *reinterpret_cast<const float4*>(&Ws[(k + kk) * N + c0 + 4]);
            #pragma unroll
            for (int r = 0; r < 8; ++r) {
                const float xs = (&xv[r].x)[kk];
                acc[r][0] += xs * w0.x; acc[r][1] += xs * w0.y;
                acc[r][2] += xs * w0.z; acc[r][3] += xs * w0.w;
                acc[r][4] += xs * w1.x; acc[r][5] += xs * w1.y;
                acc[r][6] += xs * w1.z; acc[r][7] += xs * w1.w;
            }
        }
    }

    float4 bv0 = make_float4(0.f, 0.f, 0.f, 0.f);
    float4 bv1 = make_float4(0.f, 0.f, 0.f, 0.f);
    if (bias) {
        bv0 = *reinterpret_cast<const float4*>(&bias[c0]);
        bv1 = *reinterpret_cast<const float4*>(&bias[c0 + 4]);
    }

    #pragma unroll
    for (int r = 0; r < 8; ++r) {
        const int gr = row0 + r;
        if (gr < M) {
            const float d = dinv[gr];
            if constexpr (HOUT) {
                union { __half2 h2[4]; uint4 u; } pk;
                pk.h2[0] = __floats2half2_rn(acc[r][0] * d, acc[r][1] * d);
                pk.h2[1] = __floats2half2_rn(acc[r][2] * d, acc[r][3] * d);
                pk.h2[2] = __floats2half2_rn(acc[r][4] * d, acc[r][5] * d);
                pk.h2[3] = __floats2half2_rn(acc[r][6] * d, acc[r][7] * d);
                *reinterpret_cast<uint4*>(&outh[(size_t)gr * N + c0]) = pk.u;
            } else {
                float4 v0, v1;
                v0.x = acc[r][0] * d + bv0.x; v0.y = acc[r][1] * d + bv0.y;
                v0.z = acc[r][2] * d + bv0.z; v0.w = acc[r][3] * d + bv0.w;
                v1.x = acc[r][4] * d + bv1.x; v1.y = acc[r][5] * d + bv1.y;
                v1.z = acc[r][6] * d + bv1.z; v1.w = acc[r][7] * d + bv1.w;
                *reinterpret_cast<float4*>(&out[(size_t)gr * N + c0])     = v0;
                *reinterpret_cast<float4*>(&out[(size_t)gr * N + c0 + 4]) = v1;
            }
        }
    }
}

// Wave-per-node gather aggregation over 64-dim fp16 rows (1 half/lane,
// 128B/wave-gather = one cache line). f32 accumulate. Edge-index loads are
// wave-uniform (n pinned to SGPR) -> scalar loads. Unroll 16 ~ avg degree.
//  FIRST=true : hsh = hs1;  emb[n] = acc*dinv[n] + bias (f32 out)
//               and ghalf[n] = emb[n]*dinv[n] (fp16 out, feeds agg2)
//  FIRST=false: hsh = g;    out[n] = acc (f32, feeds decode GEMM)
template<bool FIRST>
__global__ __launch_bounds__(256)
void gcn_agg(const __half* __restrict__ hsh, const int* __restrict__ csr,
             const int* __restrict__ cnt, const float* __restrict__ dinv,
             const float* __restrict__ bias, float* __restrict__ outf,
             __half* __restrict__ outh, int M, int cap)
{
    const int lane = threadIdx.x & 63;
    int n = (blockIdx.x * 256 + threadIdx.x) >> 6;
    if (n >= M) return;
    n = __builtin_amdgcn_readfirstlane(n);
    int deg = cnt[n];
    if (deg > cap) deg = cap;
    const int* __restrict__ lst = csr + (size_t)n * cap;

    float acc = __half2float(hsh[(size_t)n * 64 + lane]);

    int j = 0;
    for (; j + 16 <= deg; j += 16) {
        int   s[16];
        float v[16];
        #pragma unroll
        for (int k = 0; k < 16; ++k) s[k] = lst[j + k];
        #pragma unroll
        for (int k = 0; k < 16; ++k) v[k] = __half2float(hsh[(size_t)s[k] * 64 + lane]);
        float t = 0.f;
        #pragma unroll
        for (int k = 0; k < 16; ++k) t += v[k];
        acc += t;
    }
    for (; j + 4 <= deg; j += 4) {
        const int s0 = lst[j], s1 = lst[j + 1], s2 = lst[j + 2], s3 = lst[j + 3];
        const float v0 = __half2float(hsh[(size_t)s0 * 64 + lane]);
        const float v1 = __half2float(hsh[(size_t)s1 * 64 + lane]);
        const float v2 = __half2float(hsh[(size_t)s2 * 64 + lane]);
        const float v3 = __half2float(hsh[(size_t)s3 * 64 + lane]);
        acc += (v0 + v1) + (v2 + v3);
    }
    for (; j < deg; ++j) acc += __half2float(hsh[(size_t)lst[j] * 64 + lane]);

    if constexpr (FIRST) {
        const float dv = dinv[n];
        const float e  = acc * dv + bias[lane];
        outf[(size_t)n * 64 + lane] = e;                       // emb (f32 output)
        outh[(size_t)n * 64 + lane] = __float2half_rn(e * dv); // g = emb*dinv (fp16)
    } else {
        outf[(size_t)n * 64 + lane] = acc;                     // agg2 (f32)
    }
}

extern "C" void kernel_launch(void* const* d_in, const int* in_sizes, int n_in,
                              void* d_out, int out_size, void* d_ws, size_t ws_size,
                              hipStream_t stream)
{
    const float* x    = (const float*)d_in[0];   // [M,128]
    const int*   ei   = (const int*)  d_in[1];   // [2,E]
    const float* Wenc = (const float*)d_in[2];   // [128,64]
    const float* benc = (const float*)d_in[3];   // [64]
    const float* Wdec = (const float*)d_in[4];   // [64,128]
    const float* bdec = (const float*)d_in[5];   // [128]

    const int M = in_sizes[0] / 128;             // 100000
    const int E = in_sizes[1] / 2;               // 1600000
    const int* src  = ei;
    const int* dstv = ei + E;

    float* emb   = (float*)d_out;                       // [M,64]
    float* recon = (float*)d_out + (size_t)M * 64;      // [M,128]

    const int NB      = (M + BNODES - 1) >> BSHIFT;     // 782 buckets
    const int BSTRIDE = 3072;                           // mean 2046, +22 sigma

    // workspace layout (int units):
    //   [0,       M*32)    hs1h  (layer-1 pre-agg, fp16, M*64 halves)
    //   [M*32,    M*64)    ghalf (g = emb*dinv, fp16, M*64 halves)
    //   [M*64,    M*128)   gbuf (P1 output, 2.4M ints) UNION agg2 (f32 M*64)
    //   [M*128,   M*129)   cnt  (in-degree)
    //   [M*129,   M*130)   dinv (f32)
    //   [M*130,   +1024)   gcur (bucket counters, padded)
    //   [M*130+1024, ...)  csr  (M*cap)
    __half* hs1h  = (__half*)d_ws;
    __half* ghalf = (__half*)((int*)d_ws + (size_t)M * 32);
    int*    gbuf  = (int*)d_ws + (size_t)M * 64;
    float*  agg2  = (float*)((int*)d_ws + (size_t)M * 64);
    int*    cnt   = (int*)d_ws + (size_t)M * 128;
    float*  dinv  = (float*)((int*)d_ws + (size_t)M * 129);
    int*    gcur  = (int*)d_ws + (size_t)M * 130;
    int*    csr   = (int*)d_ws + (size_t)M * 130 + 1024;

    const size_t used = ((size_t)M * 130 + 1024) * 4;
    int cap = 64;                                        // Poisson(16): P(deg>64) ~ 1e-50
    const size_t avail = (ws_size > used) ? (ws_size - used) / ((size_t)M * 4) : 0;
    if ((size_t)cap > avail) cap = (int)avail;

    hipMemsetAsync(gcur, 0, 1024 * sizeof(int), stream);

    // ---- CSR build: partition (4096 edges/block) then per-bucket slotting ----
    part_kernel<<<(E + 4095) / 4096, 1024, 0, stream>>>(src, dstv, E, NB, gcur, gbuf, BSTRIDE);
    csr_kernel<<<NB, 256, 0, stream>>>(gcur, gbuf, BSTRIDE, csr, cap, cnt, dinv, M);

    const int aggBlocks = (M + 3) / 4;   // 4 waves (nodes) per 256-thread block

    // ---- layer 1: encode 128 -> 64 ----
    // CG=8: tile 256 rows x 64 cols, 391 blocks
    gemm_rb<128, 64, 8, true><<<(M + 255) / 256, 256, 0, stream>>>(
        x, Wenc, dinv, nullptr, nullptr, hs1h, M);
    gcn_agg<true><<<aggBlocks, 256, 0, stream>>>(
        hs1h, csr, cnt, dinv, benc, emb, ghalf, M, cap);

    // ---- layer 2: decode 64 -> 128 (aggregate in 64-dim, then GEMM) ----
    gcn_agg<false><<<aggBlocks, 256, 0, stream>>>(
        ghalf, csr, cnt, nullptr, nullptr, agg2, nullptr, M, cap);
    // CG=16: tile 128 rows x 128 cols, 782 blocks
    gemm_rb<64, 128, 16, false><<<(M + 127) / 128, 256, 0, stream>>>(
        agg2, Wdec, dinv, bdec, recon, nullptr, M);
}

// Round 6
// 292.064 us; speedup vs baseline: 1.6699x; 1.0100x over previous
//
#include <hip/hip_runtime.h>
#include <hip/hip_fp16.h>

// ---------------------------------------------------------------------------
// localAE: two GCNConv layers (128->64 encode, 64->128 decode), N=100000,
// E=1.6M.  out[n] = dinv[n] * (hs[n] + sum_{e: dst==n} hs[src_e]) + b
// where hs = (X @ W) * dinv[row],  dinv = rsqrt(1 + indegree).
//
// Round 8: re-tiled register-blocked GEMM. Round-7 gemm_rb fixed the LDS
// bottleneck but shrank the grid to 391 blocks -> Occupancy 11.5% (1.5
// waves/SIMD), latency-bound on LLC-resident X (VALUBusy 25%, 47us vs
// 10.4us f32 floor). Now 4 rows/thread (encode TM=128 -> 782 blocks,
// decode TM=64 -> 1563 blocks, ~3-5 blocks/CU) + explicit next-k-chunk X
// prefetch into registers. Numerics identical (same per-output k order).
// ---------------------------------------------------------------------------

#define BSHIFT 7                      // 128 nodes per bucket
#define BNODES (1 << BSHIFT)
#define NB_LDS 1024                   // LDS histogram capacity (NB <= 1024)

// P1: partition edges into buckets by dst>>BSHIFT, packed (src<<BSHIFT)|dloc.
// One global atomic per (block,bucket) instead of per edge (fabric-RMW wall).
__global__ __launch_bounds__(1024)
void part_kernel(const int* __restrict__ src, const int* __restrict__ dst,
                 int E, int NB, int* __restrict__ gcur, int* __restrict__ gbuf,
                 int BSTRIDE)
{
    __shared__ int hist[NB_LDS];
    __shared__ int bbase[NB_LDS];
    const int tid = threadIdx.x;
    for (int i = tid; i < NB; i += 1024) hist[i] = 0;
    __syncthreads();

    const int base = (blockIdx.x * 1024 + tid) * 4;
    int bk[4], lp[4], pk[4];
    int nv = 0;
    if (base + 4 <= E) {
        const int4 d4 = *reinterpret_cast<const int4*>(dst + base);
        const int4 s4 = *reinterpret_cast<const int4*>(src + base);
        nv = 4;
        #pragma unroll
        for (int k = 0; k < 4; ++k) {
            const int d = (&d4.x)[k];
            bk[k] = d >> BSHIFT;
            pk[k] = ((&s4.x)[k] << BSHIFT) | (d & (BNODES - 1));
            lp[k] = atomicAdd(&hist[bk[k]], 1);
        }
    } else {
        for (int k = 0; base + k < E && k < 4; ++k) {
            const int d = dst[base + k];
            bk[nv] = d >> BSHIFT;
            pk[nv] = (src[base + k] << BSHIFT) | (d & (BNODES - 1));
            lp[nv] = atomicAdd(&hist[bk[nv]], 1);
            ++nv;
        }
    }
    __syncthreads();
    for (int i = tid; i < NB; i += 1024) {
        const int c = hist[i];
        bbase[i] = c ? atomicAdd(&gcur[i], c) : 0;   // one device atomic per (block,bucket)
    }
    __syncthreads();
    for (int k = 0; k < nv; ++k) {
        const int pos = bbase[bk[k]] + lp[k];
        if (pos < BSTRIDE) gbuf[(size_t)bk[k] * BSTRIDE + pos] = pk[k];
    }
}

// P2: per bucket (128 nodes), slot edges into CSR rows via LDS cursors
// (zero fabric RMW); CSR writes confined to a 32KB region -> merge in L2.
// Degree count + dinv fused.
__global__ __launch_bounds__(256)
void csr_kernel(const int* __restrict__ gcur, const int* __restrict__ gbuf,
                int BSTRIDE, int* __restrict__ csr, int cap,
                int* __restrict__ cnt, float* __restrict__ dinv, int M)
{
    __shared__ int cur[BNODES];
    const int tid = threadIdx.x;
    const int b   = blockIdx.x;
    if (tid < BNODES) cur[tid] = 0;
    __syncthreads();

    int nb = gcur[b];
    if (nb > BSTRIDE) nb = BSTRIDE;
    const int* __restrict__ buf = gbuf + (size_t)b * BSTRIDE;
    const int n0 = b << BSHIFT;

    for (int i = tid; i < nb; i += 256) {
        const int p = buf[i];
        const int d = p & (BNODES - 1);
        const int s = p >> BSHIFT;
        const int lpos = atomicAdd(&cur[d], 1);        // LDS atomic
        if (lpos < cap) csr[(size_t)(n0 + d) * cap + lpos] = s;
    }
    __syncthreads();
    const int n = n0 + tid;
    if (tid < BNODES && n < M) {
        const int c = cur[tid];
        cnt[n]  = c;                                   // true in-degree
        dinv[n] = rsqrtf((float)c + 1.0f);             // +1 self-loop
    }
}

// Register-blocked GEMM: out[m,:] = (X[m,:] @ W) * dinv[m] (+ bias).
// 256 threads as CG col-groups x RG row-groups; each thread computes an
// R-row x 8-col output tile. W staged in LDS (32KB, broadcast b128 reads);
// X read from global through L1 (wave dedups the CG same-address lanes; a
// 64B line covers 4 k-chunks), next k-chunk prefetched into registers.
template<int K, int N, int CG, int R, bool HOUT>
__global__ __launch_bounds__(256)
void gemm_rb(const float* __restrict__ X, const float* __restrict__ W,
             const float* __restrict__ dinv, const float* __restrict__ bias,
             float* __restrict__ out, __half* __restrict__ outh, int M)
{
    constexpr int RG = 256 / CG;
    constexpr int TM = RG * R;
    __shared__ float Ws[K * N];

    const int tid = threadIdx.x;
    for (int i = tid; i < K * N / 4; i += 256)
        reinterpret_cast<float4*>(Ws)[i] = reinterpret_cast<const float4*>(W)[i];
    __syncthreads();

    const int cg   = tid % CG;
    const int rg   = tid / CG;
    const int c0   = cg * 8;
    const int row0 = blockIdx.x * TM + rg * R;

    float acc[R][8];
    #pragma unroll
    for (int r = 0; r < R; ++r)
        #pragma unroll
        for (int c = 0; c < 8; ++c) acc[r][c] = 0.f;

    const float* xp[R];
    #pragma unroll
    for (int r = 0; r < R; ++r) {
        int rr = row0 + r;
        if (rr >= M) rr = M - 1;                  // clamp loads; stores guarded
        xp[r] = X + (size_t)rr * K;
    }

    float4 xv[R];
    #pragma unroll
    for (int r = 0; r < R; ++r) xv[r] = *reinterpret_cast<const float4*>(xp[r]);

    for (int k = 0; k < K; k += 4) {
        float4 xn[R];
        const bool more = (k + 4 < K);
        if (more) {
            #pragma unroll
            for (int r = 0; r < R; ++r)
                xn[r] = *reinterpret_cast<const float4*>(xp[r] + k + 4);
        }
        #pragma unroll
        for (int kk = 0; kk < 4; ++kk) {
            const float4 w0 = *reinterpret_cast<const float4*>(&Ws[(k + kk) * N + c0]);
            const float4 w1 = *reinterpret_cast<const float4*>(&Ws[(k + kk) * N + c0 + 4]);
            #pragma unroll
            for (int r = 0; r < R; ++r) {
                const float xs = (&xv[r].x)[kk];
                acc[r][0] += xs * w0.x; acc[r][1] += xs * w0.y;
                acc[r][2] += xs * w0.z; acc[r][3] += xs * w0.w;
                acc[r][4] += xs * w1.x; acc[r][5] += xs * w1.y;
                acc[r][6] += xs * w1.z; acc[r][7] += xs * w1.w;
            }
        }
        if (more) {
            #pragma unroll
            for (int r = 0; r < R; ++r) xv[r] = xn[r];
        }
    }

    float4 bv0 = make_float4(0.f, 0.f, 0.f, 0.f);
    float4 bv1 = make_float4(0.f, 0.f, 0.f, 0.f);
    if (bias) {
        bv0 = *reinterpret_cast<const float4*>(&bias[c0]);
        bv1 = *reinterpret_cast<const float4*>(&bias[c0 + 4]);
    }

    #pragma unroll
    for (int r = 0; r < R; ++r) {
        const int gr = row0 + r;
        if (gr < M) {
            const float d = dinv[gr];
            if constexpr (HOUT) {
                union { __half2 h2[4]; uint4 u; } pk;
                pk.h2[0] = __floats2half2_rn(acc[r][0] * d, acc[r][1] * d);
                pk.h2[1] = __floats2half2_rn(acc[r][2] * d, acc[r][3] * d);
                pk.h2[2] = __floats2half2_rn(acc[r][4] * d, acc[r][5] * d);
                pk.h2[3] = __floats2half2_rn(acc[r][6] * d, acc[r][7] * d);
                *reinterpret_cast<uint4*>(&outh[(size_t)gr * N + c0]) = pk.u;
            } else {
                float4 v0, v1;
                v0.x = acc[r][0] * d + bv0.x; v0.y = acc[r][1] * d + bv0.y;
                v0.z = acc[r][2] * d + bv0.z; v0.w = acc[r][3] * d + bv0.w;
                v1.x = acc[r][4] * d + bv1.x; v1.y = acc[r][5] * d + bv1.y;
                v1.z = acc[r][6] * d + bv1.z; v1.w = acc[r][7] * d + bv1.w;
                *reinterpret_cast<float4*>(&out[(size_t)gr * N + c0])     = v0;
                *reinterpret_cast<float4*>(&out[(size_t)gr * N + c0 + 4]) = v1;
            }
        }
    }
}

// Wave-per-node gather aggregation over 64-dim fp16 rows (1 half/lane,
// 128B/wave-gather = one cache line). f32 accumulate. Edge-index loads are
// wave-uniform (n pinned to SGPR) -> scalar loads. Unroll 16 ~ avg degree.
//  FIRST=true : hsh = hs1;  emb[n] = acc*dinv[n] + bias (f32 out)
//               and ghalf[n] = emb[n]*dinv[n] (fp16 out, feeds agg2)
//  FIRST=false: hsh = g;    out[n] = acc (f32, feeds decode GEMM)
template<bool FIRST>
__global__ __launch_bounds__(256)
void gcn_agg(const __half* __restrict__ hsh, const int* __restrict__ csr,
             const int* __restrict__ cnt, const float* __restrict__ dinv,
             const float* __restrict__ bias, float* __restrict__ outf,
             __half* __restrict__ outh, int M, int cap)
{
    const int lane = threadIdx.x & 63;
    int n = (blockIdx.x * 256 + threadIdx.x) >> 6;
    if (n >= M) return;
    n = __builtin_amdgcn_readfirstlane(n);
    int deg = cnt[n];
    if (deg > cap) deg = cap;
    const int* __restrict__ lst = csr + (size_t)n * cap;

    float acc = __half2float(hsh[(size_t)n * 64 + lane]);

    int j = 0;
    for (; j + 16 <= deg; j += 16) {
        int   s[16];
        float v[16];
        #pragma unroll
        for (int k = 0; k < 16; ++k) s[k] = lst[j + k];
        #pragma unroll
        for (int k = 0; k < 16; ++k) v[k] = __half2float(hsh[(size_t)s[k] * 64 + lane]);
        float t = 0.f;
        #pragma unroll
        for (int k = 0; k < 16; ++k) t += v[k];
        acc += t;
    }
    for (; j + 4 <= deg; j += 4) {
        const int s0 = lst[j], s1 = lst[j + 1], s2 = lst[j + 2], s3 = lst[j + 3];
        const float v0 = __half2float(hsh[(size_t)s0 * 64 + lane]);
        const float v1 = __half2float(hsh[(size_t)s1 * 64 + lane]);
        const float v2 = __half2float(hsh[(size_t)s2 * 64 + lane]);
        const float v3 = __half2float(hsh[(size_t)s3 * 64 + lane]);
        acc += (v0 + v1) + (v2 + v3);
    }
    for (; j < deg; ++j) acc += __half2float(hsh[(size_t)lst[j] * 64 + lane]);

    if constexpr (FIRST) {
        const float dv = dinv[n];
        const float e  = acc * dv + bias[lane];
        outf[(size_t)n * 64 + lane] = e;                       // emb (f32 output)
        outh[(size_t)n * 64 + lane] = __float2half_rn(e * dv); // g = emb*dinv (fp16)
    } else {
        outf[(size_t)n * 64 + lane] = acc;                     // agg2 (f32)
    }
}

extern "C" void kernel_launch(void* const* d_in, const int* in_sizes, int n_in,
                              void* d_out, int out_size, void* d_ws, size_t ws_size,
                              hipStream_t stream)
{
    const float* x    = (const float*)d_in[0];   // [M,128]
    const int*   ei   = (const int*)  d_in[1];   // [2,E]
    const float* Wenc = (const float*)d_in[2];   // [128,64]
    const float* benc = (const float*)d_in[3];   // [64]
    const float* Wdec = (const float*)d_in[4];   // [64,128]
    const float* bdec = (const float*)d_in[5];   // [128]

    const int M = in_sizes[0] / 128;             // 100000
    const int E = in_sizes[1] / 2;               // 1600000
    const int* src  = ei;
    const int* dstv = ei + E;

    float* emb   = (float*)d_out;                       // [M,64]
    float* recon = (float*)d_out + (size_t)M * 64;      // [M,128]

    const int NB      = (M + BNODES - 1) >> BSHIFT;     // 782 buckets
    const int BSTRIDE = 3072;                           // mean 2046, +22 sigma

    // workspace layout (int units):
    //   [0,       M*32)    hs1h  (layer-1 pre-agg, fp16, M*64 halves)
    //   [M*32,    M*64)    ghalf (g = emb*dinv, fp16, M*64 halves)
    //   [M*64,    M*128)   gbuf (P1 output, 2.4M ints) UNION agg2 (f32 M*64)
    //   [M*128,   M*129)   cnt  (in-degree)
    //   [M*129,   M*130)   dinv (f32)
    //   [M*130,   +1024)   gcur (bucket counters, padded)
    //   [M*130+1024, ...)  csr  (M*cap)
    __half* hs1h  = (__half*)d_ws;
    __half* ghalf = (__half*)((int*)d_ws + (size_t)M * 32);
    int*    gbuf  = (int*)d_ws + (size_t)M * 64;
    float*  agg2  = (float*)((int*)d_ws + (size_t)M * 64);
    int*    cnt   = (int*)d_ws + (size_t)M * 128;
    float*  dinv  = (float*)((int*)d_ws + (size_t)M * 129);
    int*    gcur  = (int*)d_ws + (size_t)M * 130;
    int*    csr   = (int*)d_ws + (size_t)M * 130 + 1024;

    const size_t used = ((size_t)M * 130 + 1024) * 4;
    int cap = 64;                                        // Poisson(16): P(deg>64) ~ 1e-50
    const size_t avail = (ws_size > used) ? (ws_size - used) / ((size_t)M * 4) : 0;
    if ((size_t)cap > avail) cap = (int)avail;

    hipMemsetAsync(gcur, 0, 1024 * sizeof(int), stream);

    // ---- CSR build: partition (4096 edges/block) then per-bucket slotting ----
    part_kernel<<<(E + 4095) / 4096, 1024, 0, stream>>>(src, dstv, E, NB, gcur, gbuf, BSTRIDE);
    csr_kernel<<<NB, 256, 0, stream>>>(gcur, gbuf, BSTRIDE, csr, cap, cnt, dinv, M);

    const int aggBlocks = (M + 3) / 4;   // 4 waves (nodes) per 256-thread block

    // ---- layer 1: encode 128 -> 64 ----
    // CG=8 x R=4: tile 128 rows x 64 cols, 782 blocks (~3/CU)
    gemm_rb<128, 64, 8, 4, true><<<(M + 127) / 128, 256, 0, stream>>>(
        x, Wenc, dinv, nullptr, nullptr, hs1h, M);
    gcn_agg<true><<<aggBlocks, 256, 0, stream>>>(
        hs1h, csr, cnt, dinv, benc, emb, ghalf, M, cap);

    // ---- layer 2: decode 64 -> 128 (aggregate in 64-dim, then GEMM) ----
    gcn_agg<false><<<aggBlocks, 256, 0, stream>>>(
        ghalf, csr, cnt, nullptr, nullptr, agg2, nullptr, M, cap);
    // CG=16 x R=4: tile 64 rows x 128 cols, 1563 blocks (~6/CU, LDS caps 5)
    gemm_rb<64, 128, 16, 4, false><<<(M + 63) / 64, 256, 0, stream>>>(
        agg2, Wdec, dinv, bdec, recon, nullptr, M);
}